// Round 1
// baseline (59.636 us; speedup 1.0000x reference)
//
#include <hip/hip_runtime.h>
#include <hip/hip_bf16.h>
#include <cstdint>

#define BM 32
#define NTHREADS 320
#define WS_TILE 524288            // 64 u-steps * 8192 bytes per weight tensor (bf16 64x64)
#define WBUF_BYTES 24576          // 3 tiles * 8192 B
#define SMEM_BYTES (2*WBUF_BYTES + 4*64*32*4)   // 49152 + 32768 = 81920

typedef __bf16 bf16x8_t __attribute__((ext_vector_type(8)));
typedef float f32x4_t __attribute__((ext_vector_type(4)));

__device__ __forceinline__ void async_ld16(const void* g, void* l) {
  __builtin_amdgcn_global_load_lds((const __attribute__((address_space(1))) unsigned int*)g,
                                   (__attribute__((address_space(3))) unsigned int*)l,
                                   16, 0, 0);
}

// Prep: fold scales, combine w011 + w101^T(u,v), transpose to [u][w][v] bf16 with
// XOR-swizzled in-tile byte layout: off(w,v) = (w*128 + v*2) ^ ((w&7)<<4).
__global__ __launch_bounds__(256) void prep_weights(const float* __restrict__ w000,
                                                    const float* __restrict__ w110,
                                                    const float* __restrict__ w011,
                                                    const float* __restrict__ w101,
                                                    char* __restrict__ ws) {
  const float A0  = 0.011048543456039806f;   // sqrt(1/8192) ; also == ALPHA1/sqrt(3)
  const float A0I = A0 * 0.57735026918962576f;
  int t = blockIdx.x * 256 + threadIdx.x;    // 32768 threads: (u, c, w)
  int u = t >> 9, c = (t >> 6) & 7, w = t & 63;
  bf16x8_t p0, p1, pc;
#pragma unroll
  for (int j = 0; j < 8; ++j) {
    int v = 8 * c + j;
    float a = w000[u * 4096 + v * 64 + w] * A0;
    float b = w110[u * 4096 + v * 64 + w] * A0I;
    float d = (w011[u * 4096 + v * 64 + w] + w101[v * 4096 + u * 64 + w]) * A0;
    p0[j] = (__bf16)a;
    p1[j] = (__bf16)b;
    pc[j] = (__bf16)d;
  }
  int off = ((w * 128 + 16 * c) ^ ((w & 7) << 4)) + u * 8192;
  *(bf16x8_t*)(ws + off) = p0;
  *(bf16x8_t*)(ws + WS_TILE + off) = p1;
  *(bf16x8_t*)(ws + 2 * WS_TILE + off) = pc;
}

// Main: 256 blocks x 320 threads. BM=32 batch rows per block.
// wave 0: p000 ; wave 1: p110 (dot3 A) ; waves 2-4: out1 k = wave-2.
__global__ __launch_bounds__(NTHREADS) void tp_main(const float* __restrict__ x,
                                                    const char* __restrict__ ws,
                                                    float* __restrict__ out) {
  extern __shared__ char smem[];
  float* xS = (float*)(smem + 2 * WBUF_BYTES);   // [vec][u][b] f32, 4*64*32
  const int tid = threadIdx.x;
  const int wave = tid >> 6, lane = tid & 63;
  const int lr = lane & 15, lg = lane >> 4;
  const int b0 = blockIdx.x * BM;
  const int role = wave;

  // stage u=0 into buffer 0 (waves 0..2, one 8KB tile each, 8 x 1KB chunks)
  if (wave < 3) {
    const char* g = ws + wave * WS_TILE + lane * 16;
#pragma unroll
    for (int c = 0; c < 8; ++c)
      async_ld16(g + c * 1024, smem + wave * 8192 + c * 1024);
  }

  // fill scalar table xS[vec][u][b]: vec0 = x0, vec 1+i = x1[:,:,i]
  for (int idx = tid; idx < 4 * 64 * 32; idx += NTHREADS) {
    int vec = idx >> 11, rem = idx & 2047;
    int uu = rem >> 5, bb = rem & 31;
    int col = (vec == 0) ? uu : (64 + 3 * uu + (vec - 1));
    xS[idx] = x[(b0 + bb) * 256 + col];
  }

  // per-wave x row-vector fragments in registers: xp[vi][m][kf][j] at
  // b = 16m + lr, v = 8*lg + 32*kf + j
  float xp[3][2][2][8];
  if (role == 1) {
#pragma unroll
    for (int vi = 0; vi < 3; ++vi)
#pragma unroll
      for (int m = 0; m < 2; ++m)
#pragma unroll
        for (int kf = 0; kf < 2; ++kf)
#pragma unroll
          for (int j = 0; j < 8; ++j) {
            int v = 8 * lg + 32 * kf + j;
            xp[vi][m][kf][j] = x[(b0 + 16 * m + lr) * 256 + 64 + 3 * v + vi];
          }
  } else {
    const int vsel = (role == 0) ? 0 : (role - 1);
#pragma unroll
    for (int m = 0; m < 2; ++m)
#pragma unroll
      for (int kf = 0; kf < 2; ++kf)
#pragma unroll
        for (int j = 0; j < 8; ++j) {
          int v = 8 * lg + 32 * kf + j;
          int col = (vsel == 0) ? v : (64 + 3 * v + (vsel - 1));
          xp[0][m][kf][j] = x[(b0 + 16 * m + lr) * 256 + col];
        }
  }

  f32x4_t acc[2][4];
#pragma unroll
  for (int m = 0; m < 2; ++m)
#pragma unroll
    for (int n = 0; n < 4; ++n) {
      f32x4_t z = {0.f, 0.f, 0.f, 0.f};
      acc[m][n] = z;
    }

  __syncthreads();   // drains vmcnt (stage u=0 complete) + xS visible

  const int tsel = (role == 0) ? 0 : ((role == 1) ? 1 : 2);
  int cur = 0;
  for (int u = 0; u < 64; ++u) {
    // issue next tile's async loads before compute
    if (u < 63 && wave < 3) {
      const char* g = ws + wave * WS_TILE + (u + 1) * 8192 + lane * 16;
#pragma unroll
      for (int c = 0; c < 8; ++c)
        async_ld16(g + c * 1024, smem + (cur ^ 1) * WBUF_BYTES + wave * 8192 + c * 1024);
    }

    // B fragments from swizzled LDS tile
    const char* wt = smem + cur * WBUF_BYTES + tsel * 8192;
    bf16x8_t bfr[4][2];
#pragma unroll
    for (int n = 0; n < 4; ++n)
#pragma unroll
      for (int kf = 0; kf < 2; ++kf) {
        int wrow = 16 * n + lr;
        int off = ((wrow * 128 + (8 * lg + 32 * kf) * 2) ^ ((wrow & 7) << 4));
        bfr[n][kf] = *(const bf16x8_t*)(wt + off);
      }

    // A fragments: scalar(u) * xvec, built in registers
    bf16x8_t afr[2][2];
    if (role == 1) {
      float s0a = xS[1 * 2048 + u * 32 + lr],      s1a = xS[2 * 2048 + u * 32 + lr],      s2a = xS[3 * 2048 + u * 32 + lr];
      float s0b = xS[1 * 2048 + u * 32 + 16 + lr], s1b = xS[2 * 2048 + u * 32 + 16 + lr], s2b = xS[3 * 2048 + u * 32 + 16 + lr];
#pragma unroll
      for (int kf = 0; kf < 2; ++kf)
#pragma unroll
        for (int j = 0; j < 8; ++j) {
          afr[0][kf][j] = (__bf16)(s0a * xp[0][0][kf][j] + s1a * xp[1][0][kf][j] + s2a * xp[2][0][kf][j]);
          afr[1][kf][j] = (__bf16)(s0b * xp[0][1][kf][j] + s1b * xp[1][1][kf][j] + s2b * xp[2][1][kf][j]);
        }
    } else {
      float sa = xS[u * 32 + lr], sb = xS[u * 32 + 16 + lr];
#pragma unroll
      for (int kf = 0; kf < 2; ++kf)
#pragma unroll
        for (int j = 0; j < 8; ++j) {
          afr[0][kf][j] = (__bf16)(sa * xp[0][0][kf][j]);
          afr[1][kf][j] = (__bf16)(sb * xp[0][1][kf][j]);
        }
    }

#pragma unroll
    for (int m = 0; m < 2; ++m)
#pragma unroll
      for (int n = 0; n < 4; ++n)
#pragma unroll
        for (int kf = 0; kf < 2; ++kf)
          acc[m][n] = __builtin_amdgcn_mfma_f32_16x16x32_bf16(afr[m][kf], bfr[n][kf], acc[m][n], 0, 0, 0);

    __syncthreads();   // next buffer staged (vmcnt drained) + this buffer free
    cur ^= 1;
  }

  // epilogue: out0 = p000 + p110 (cross-wave via LDS), out1 strided store
  float* pscr = (float*)smem;   // 32x64 f32, reuses weight buffer (all reads done)
  if (role == 1) {
#pragma unroll
    for (int m = 0; m < 2; ++m)
#pragma unroll
      for (int n = 0; n < 4; ++n)
#pragma unroll
        for (int r = 0; r < 4; ++r)
          pscr[(16 * m + 4 * lg + r) * 64 + 16 * n + lr] = acc[m][n][r];
  }
  __syncthreads();
  if (role == 0) {
#pragma unroll
    for (int m = 0; m < 2; ++m)
#pragma unroll
      for (int n = 0; n < 4; ++n)
#pragma unroll
        for (int r = 0; r < 4; ++r) {
          int row = 16 * m + 4 * lg + r, col = 16 * n + lr;
          out[(b0 + row) * 256 + col] = acc[m][n][r] + pscr[row * 64 + col];
        }
  } else if (role >= 2) {
    const int k = role - 2;
#pragma unroll
    for (int m = 0; m < 2; ++m)
#pragma unroll
      for (int n = 0; n < 4; ++n)
#pragma unroll
        for (int r = 0; r < 4; ++r) {
          int row = 16 * m + 4 * lg + r, col = 16 * n + lr;
          out[(b0 + row) * 256 + 64 + 3 * col + k] = acc[m][n][r];
        }
  }
}

extern "C" void kernel_launch(void* const* d_in, const int* in_sizes, int n_in,
                              void* d_out, int out_size, void* d_ws, size_t ws_size,
                              hipStream_t stream) {
  const float* x    = (const float*)d_in[0];
  const float* w000 = (const float*)d_in[1];
  const float* w110 = (const float*)d_in[2];
  const float* w011 = (const float*)d_in[3];
  const float* w101 = (const float*)d_in[4];
  float* out = (float*)d_out;
  char* ws = (char*)d_ws;

  prep_weights<<<128, 256, 0, stream>>>(w000, w110, w011, w101, ws);

  hipFuncSetAttribute((const void*)tp_main, hipFuncAttributeMaxDynamicSharedMemorySize, SMEM_BYTES);
  tp_main<<<256, NTHREADS, SMEM_BYTES, stream>>>(x, ws, out);
}